// Round 9
// baseline (1071.256 us; speedup 1.0000x reference)
//
#include <hip/hip_runtime.h>

#define DD 64
#define TT 8192
#define KK 2048
#define NTROWS 65536

// d_out layout (float offsets), matching reference return order:
// xd[8*64*8192] | codes[65536] | commit[1] | k_new[131072] | k_sum_n[131072] | k_elem_n[2048]
#define OFF_CODES  4194304ull
#define OFF_COMMIT 4259840ull
#define OFF_KNEW   4259841ull
#define OFF_KSUM   4390913ull
#define OFF_KELEM  4521985ull

#define SQ(a) __fmul_rn((a), (a))

// ---------------- prep: sk[c] = np.sum(k[c]*k[c]) in replicated fp32 ----------
__global__ __launch_bounds__(256) void vq_prep(const float* __restrict__ k,
                                               float* __restrict__ sk) {
  int c = blockIdx.x * 256 + threadIdx.x;
  if (c < KK) {
    const float* v = k + (size_t)c * DD;
    float r[8];
#pragma unroll
    for (int j = 0; j < 8; ++j) r[j] = SQ(v[j]);
#pragma unroll
    for (int i = 8; i < 64; i += 8) {
#pragma unroll
      for (int j = 0; j < 8; ++j) r[j] = __fadd_rn(r[j], SQ(v[i + j]));
    }
    sk[c] = __fadd_rn(
        __fadd_rn(__fadd_rn(r[0], r[1]), __fadd_rn(r[2], r[3])),
        __fadd_rn(__fadd_rn(r[4], r[5]), __fadd_rn(r[6], r[7])));
  }
}

// ---------------- argmin: wave-uniform k, lane = row (validated) ----------------
__global__ __launch_bounds__(256) void vq_argmin(
    const float* __restrict__ x, const float* __restrict__ k,
    const float* __restrict__ sk, float* __restrict__ out_codes) {
  __shared__ float xs[64][65];       // 16640 B
  __shared__ float bv[4][64];
  __shared__ int bi[4][64];

  const int lane = threadIdx.x & 63;       // row within block
  const int wv = threadIdx.x >> 6;         // code quarter

  const int R0 = blockIdx.x * 64;
  const int n = R0 >> 13;                  // T = 8192
  const int t0 = R0 & (TT - 1);

  // ---- stage 64 rows into LDS, coalesced ----
  {
    const float* xb = x + (size_t)n * (DD * TT) + t0;
    const int tt = threadIdx.x & 63;
    const int dq = threadIdx.x >> 6;       // 0..3
#pragma unroll
    for (int chunk = 0; chunk < 16; ++chunk) {
      const int d = chunk * 4 + dq;
      xs[tt][d] = xb[(size_t)d * TT + tt];
    }
  }
  __syncthreads();

  // np's ||x||^2: 8 accumulators over stride-8 elements, fixed fold tree
  float sumx;
  {
    float rr[8];
#pragma unroll
    for (int j = 0; j < 8; ++j) rr[j] = SQ(xs[lane][j]);
#pragma unroll
    for (int i = 8; i < 64; i += 8) {
#pragma unroll
      for (int j = 0; j < 8; ++j) rr[j] = __fadd_rn(rr[j], SQ(xs[lane][i + j]));
    }
    sumx = __fadd_rn(
        __fadd_rn(__fadd_rn(rr[0], rr[1]), __fadd_rn(rr[2], rr[3])),
        __fadd_rn(__fadd_rn(rr[4], rr[5]), __fadd_rn(rr[6], rr[7])));
  }

  // wave-uniform code base (force SGPR)
  const int qbase = __builtin_amdgcn_readfirstlane(wv) * (KK / 4);

  float best = 3.402823466e38f;
  int bidx = 0;
  for (int cc = 0; cc < KK / 4; cc += 4) {
    const int c0 = qbase + cc;
    const float4* kp0 = (const float4*)(k + (size_t)c0 * DD);        // uniform
    const float4* kp1 = kp0 + 16;
    const float4* kp2 = kp0 + 32;
    const float4* kp3 = kp0 + 48;
    float a0 = 0.f, a1 = 0.f, a2 = 0.f, a3 = 0.f;
#pragma unroll
    for (int i = 0; i < 16; ++i) {
      const float4 xv = *(const float4*)&xs[lane][4 * i];  // one read, 4 codes
      const float4 kv0 = kp0[i];
      const float4 kv1 = kp1[i];
      const float4 kv2 = kp2[i];
      const float4 kv3 = kp3[i];
      a0 = fmaf(xv.x, kv0.x, a0);
      a1 = fmaf(xv.x, kv1.x, a1);
      a2 = fmaf(xv.x, kv2.x, a2);
      a3 = fmaf(xv.x, kv3.x, a3);
      a0 = fmaf(xv.y, kv0.y, a0);
      a1 = fmaf(xv.y, kv1.y, a1);
      a2 = fmaf(xv.y, kv2.y, a2);
      a3 = fmaf(xv.y, kv3.y, a3);
      a0 = fmaf(xv.z, kv0.z, a0);
      a1 = fmaf(xv.z, kv1.z, a1);
      a2 = fmaf(xv.z, kv2.z, a2);
      a3 = fmaf(xv.z, kv3.z, a3);
      a0 = fmaf(xv.w, kv0.w, a0);
      a1 = fmaf(xv.w, kv1.w, a1);
      a2 = fmaf(xv.w, kv2.w, a2);
      a3 = fmaf(xv.w, kv3.w, a3);
    }
    const float d0 = __fadd_rn(__fsub_rn(sumx, __fmul_rn(2.0f, a0)), sk[c0]);
    const float d1 = __fadd_rn(__fsub_rn(sumx, __fmul_rn(2.0f, a1)), sk[c0 + 1]);
    const float d2 = __fadd_rn(__fsub_rn(sumx, __fmul_rn(2.0f, a2)), sk[c0 + 2]);
    const float d3 = __fadd_rn(__fsub_rn(sumx, __fmul_rn(2.0f, a3)), sk[c0 + 3]);
    if (d0 < best) { best = d0; bidx = c0; }   // strict < -> first index wins
    if (d1 < best) { best = d1; bidx = c0 + 1; }
    if (d2 < best) { best = d2; bidx = c0 + 2; }
    if (d3 < best) { best = d3; bidx = c0 + 3; }
  }

  // cross-wave combine: quarters ascending, strict < keeps lowest index
  bv[wv][lane] = best;
  bi[wv][lane] = bidx;
  __syncthreads();
  if (threadIdx.x < 64) {
    float v = bv[0][threadIdx.x];
    int ii = bi[0][threadIdx.x];
#pragma unroll
    for (int qq = 1; qq < 4; ++qq) {
      const float ov = bv[qq][threadIdx.x];
      if (ov < v) { v = ov; ii = bi[qq][threadIdx.x]; }
    }
    out_codes[R0 + threadIdx.x] = (float)ii;
  }
}

// ---------------- epilogue: gather, xd, commit, EMA scatter ----------------
// Grid (1024, 4) x 256 threads = 1 M threads, 16 blocks/CU. Thread =
// (row, 4 dims): 1 float4 k-gather + 4 coalesced x loads + 4 coalesced xd
// stores + 4 scattered atomics. Round-8's 256-block version starved on
// VMEM latency (Occ 9.5%, VALUBusy 0.1%, 757 us for 4.2M atomics).
__global__ __launch_bounds__(256) void vq_epi(
    const float* __restrict__ x, const float* __restrict__ k,
    const float* __restrict__ codes_f, float* __restrict__ out_xd,
    float* __restrict__ commit_acc, float* __restrict__ sum_acc,
    float* __restrict__ cnt_acc) {
  const int lane = threadIdx.x & 63;
  const int q = threadIdx.x >> 6;          // 0..3
  const int row = blockIdx.x * 64 + lane;
  const int n = row >> 13;
  const int t = row & (TT - 1);
  const int d0 = blockIdx.y * 16 + q * 4;  // this thread's 4 dims

  const int code = (int)codes_f[row];

  const float* xp = x + (size_t)n * (DD * TT) + t;
  float* xd_base = out_xd + (size_t)n * (DD * TT) + t;

  // one float4 gather covers this thread's 4 k values
  const float4 kq = ((const float4*)k)[(size_t)code * 16 + (d0 >> 2)];

  float csum = 0.f;
#pragma unroll
  for (int j = 0; j < 4; ++j) {
    const int d = d0 + j;
    const float xqv = (j == 0) ? kq.x : (j == 1) ? kq.y : (j == 2) ? kq.z : kq.w;
    const float xv = xp[(size_t)d * TT];       // coalesced across lanes
    const float diff = __fsub_rn(xqv, xv);
    xd_base[(size_t)d * TT] = __fadd_rn(xv, diff);
    csum = fmaf(diff, diff, csum);
    atomicAdd(&sum_acc[(size_t)code * DD + d], xv);
  }
  if (blockIdx.y == 0 && q == 0) atomicAdd(&cnt_acc[code], 1.0f);

  // commit: wave reduce -> LDS -> one atomic per block
  __shared__ float cs[4];
#pragma unroll
  for (int off = 32; off >= 1; off >>= 1) csum += __shfl_xor(csum, off);
  if (lane == 0) cs[q] = csum;
  __syncthreads();
  if (threadIdx.x == 0) {
    atomicAdd(commit_acc, (cs[0] + cs[1]) + (cs[2] + cs[3]));
  }
}

// ---------------- finalize: EMA buffers, k_new, commit mean ----------------
__global__ __launch_bounds__(256) void vq_finalize(
    const float* __restrict__ k, const float* __restrict__ k_sum,
    const float* __restrict__ k_elem, const float* __restrict__ cnt_raw,
    float* __restrict__ out_commit, float* __restrict__ out_knew,
    float* __restrict__ out_ksum, float* __restrict__ out_kelem) {
  const int i = blockIdx.x * 256 + threadIdx.x;
  if (i == 0) {
    out_commit[0] = out_commit[0] / 4194304.0f;
  }
  if (i < KK * DD) {
    const int c = i >> 6;
    const float cnt = cnt_raw[c];
    const float ke_n = __fadd_rn(__fmul_rn(0.99f, k_elem[c]), __fmul_rn(0.01f, cnt));
    const float s_raw = out_ksum[i];
    const float ks_n = __fadd_rn(__fmul_rn(0.99f, k_sum[i]), __fmul_rn(0.01f, s_raw));
    out_ksum[i] = ks_n;
    out_knew[i] = (ke_n >= 1.0f) ? (ks_n / ke_n) : k[i];
    if ((i & 63) == 0) out_kelem[c] = ke_n;
  }
}

extern "C" void kernel_launch(void* const* d_in, const int* in_sizes, int n_in,
                              void* d_out, int out_size, void* d_ws, size_t ws_size,
                              hipStream_t stream) {
  const float* x = (const float*)d_in[0];
  const float* k = (const float*)d_in[1];
  const float* k_sum = (const float*)d_in[2];
  const float* k_elem = (const float*)d_in[3];

  float* out = (float*)d_out;
  float* out_xd = out;
  float* out_codes = out + OFF_CODES;
  float* out_commit = out + OFF_COMMIT;
  float* out_knew = out + OFF_KNEW;
  float* out_ksum = out + OFF_KSUM;    // raw sum accumulator, finalized in place
  float* out_kelem = out + OFF_KELEM;

  char* ws = (char*)d_ws;
  float* sk = (float*)ws;              // 8 KB
  float* cnt_raw = (float*)(ws + 8192);

  hipMemsetAsync(out_ksum, 0, (size_t)KK * DD * sizeof(float), stream);
  hipMemsetAsync(cnt_raw, 0, (size_t)KK * sizeof(float), stream);
  hipMemsetAsync(out_commit, 0, sizeof(float), stream);

  vq_prep<<<(KK + 255) / 256, 256, 0, stream>>>(k, sk);

  vq_argmin<<<NTROWS / 64, 256, 0, stream>>>(x, k, sk, out_codes);

  dim3 epi_grid(NTROWS / 64, 4);
  vq_epi<<<epi_grid, 256, 0, stream>>>(x, k, out_codes, out_xd,
                                       out_commit, out_ksum, cnt_raw);

  vq_finalize<<<(KK * DD + 255) / 256, 256, 0, stream>>>(
      k, k_sum, k_elem, cnt_raw, out_commit, out_knew, out_ksum, out_kelem);
}

// Round 10
// 742.619 us; speedup vs baseline: 1.4425x; 1.4425x over previous
//
#include <hip/hip_runtime.h>

#define DD 64
#define TT 8192
#define KK 2048
#define NTROWS 65536

// d_out layout (float offsets), matching reference return order:
// xd[8*64*8192] | codes[65536] | commit[1] | k_new[131072] | k_sum_n[131072] | k_elem_n[2048]
#define OFF_CODES  4194304ull
#define OFF_COMMIT 4259840ull
#define OFF_KNEW   4259841ull
#define OFF_KSUM   4390913ull
#define OFF_KELEM  4521985ull

#define SQ(a) __fmul_rn((a), (a))

// ws layout (bytes): sk f32 [0,8K) | cnt_int [8K,16K) | cursor [16K,24K)
// | commit partials f32 [24K,40K) | bucket int [40K, 40K+256K)

// ---------------- prep: sk[c] = np.sum(k[c]*k[c]) in replicated fp32 ----------
__global__ __launch_bounds__(256) void vq_prep(const float* __restrict__ k,
                                               float* __restrict__ sk) {
  int c = blockIdx.x * 256 + threadIdx.x;
  if (c < KK) {
    const float* v = k + (size_t)c * DD;
    float r[8];
#pragma unroll
    for (int j = 0; j < 8; ++j) r[j] = SQ(v[j]);
#pragma unroll
    for (int i = 8; i < 64; i += 8) {
#pragma unroll
      for (int j = 0; j < 8; ++j) r[j] = __fadd_rn(r[j], SQ(v[i + j]));
    }
    sk[c] = __fadd_rn(
        __fadd_rn(__fadd_rn(r[0], r[1]), __fadd_rn(r[2], r[3])),
        __fadd_rn(__fadd_rn(r[4], r[5]), __fadd_rn(r[6], r[7])));
  }
}

// ---------------- argmin: wave-uniform k, lane = row (validated) ----------------
__global__ __launch_bounds__(256) void vq_argmin(
    const float* __restrict__ x, const float* __restrict__ k,
    const float* __restrict__ sk, float* __restrict__ out_codes) {
  __shared__ float xs[64][65];       // 16640 B
  __shared__ float bv[4][64];
  __shared__ int bi[4][64];

  const int lane = threadIdx.x & 63;       // row within block
  const int wv = threadIdx.x >> 6;         // code quarter

  const int R0 = blockIdx.x * 64;
  const int n = R0 >> 13;                  // T = 8192
  const int t0 = R0 & (TT - 1);

  // ---- stage 64 rows into LDS, coalesced ----
  {
    const float* xb = x + (size_t)n * (DD * TT) + t0;
    const int tt = threadIdx.x & 63;
    const int dq = threadIdx.x >> 6;       // 0..3
#pragma unroll
    for (int chunk = 0; chunk < 16; ++chunk) {
      const int d = chunk * 4 + dq;
      xs[tt][d] = xb[(size_t)d * TT + tt];
    }
  }
  __syncthreads();

  // np's ||x||^2: 8 accumulators over stride-8 elements, fixed fold tree
  float sumx;
  {
    float rr[8];
#pragma unroll
    for (int j = 0; j < 8; ++j) rr[j] = SQ(xs[lane][j]);
#pragma unroll
    for (int i = 8; i < 64; i += 8) {
#pragma unroll
      for (int j = 0; j < 8; ++j) rr[j] = __fadd_rn(rr[j], SQ(xs[lane][i + j]));
    }
    sumx = __fadd_rn(
        __fadd_rn(__fadd_rn(rr[0], rr[1]), __fadd_rn(rr[2], rr[3])),
        __fadd_rn(__fadd_rn(rr[4], rr[5]), __fadd_rn(rr[6], rr[7])));
  }

  // wave-uniform code base (force SGPR)
  const int qbase = __builtin_amdgcn_readfirstlane(wv) * (KK / 4);

  float best = 3.402823466e38f;
  int bidx = 0;
  for (int cc = 0; cc < KK / 4; cc += 4) {
    const int c0 = qbase + cc;
    const float4* kp0 = (const float4*)(k + (size_t)c0 * DD);        // uniform
    const float4* kp1 = kp0 + 16;
    const float4* kp2 = kp0 + 32;
    const float4* kp3 = kp0 + 48;
    float a0 = 0.f, a1 = 0.f, a2 = 0.f, a3 = 0.f;
#pragma unroll
    for (int i = 0; i < 16; ++i) {
      const float4 xv = *(const float4*)&xs[lane][4 * i];  // one read, 4 codes
      const float4 kv0 = kp0[i];
      const float4 kv1 = kp1[i];
      const float4 kv2 = kp2[i];
      const float4 kv3 = kp3[i];
      a0 = fmaf(xv.x, kv0.x, a0);
      a1 = fmaf(xv.x, kv1.x, a1);
      a2 = fmaf(xv.x, kv2.x, a2);
      a3 = fmaf(xv.x, kv3.x, a3);
      a0 = fmaf(xv.y, kv0.y, a0);
      a1 = fmaf(xv.y, kv1.y, a1);
      a2 = fmaf(xv.y, kv2.y, a2);
      a3 = fmaf(xv.y, kv3.y, a3);
      a0 = fmaf(xv.z, kv0.z, a0);
      a1 = fmaf(xv.z, kv1.z, a1);
      a2 = fmaf(xv.z, kv2.z, a2);
      a3 = fmaf(xv.z, kv3.z, a3);
      a0 = fmaf(xv.w, kv0.w, a0);
      a1 = fmaf(xv.w, kv1.w, a1);
      a2 = fmaf(xv.w, kv2.w, a2);
      a3 = fmaf(xv.w, kv3.w, a3);
    }
    const float d0 = __fadd_rn(__fsub_rn(sumx, __fmul_rn(2.0f, a0)), sk[c0]);
    const float d1 = __fadd_rn(__fsub_rn(sumx, __fmul_rn(2.0f, a1)), sk[c0 + 1]);
    const float d2 = __fadd_rn(__fsub_rn(sumx, __fmul_rn(2.0f, a2)), sk[c0 + 2]);
    const float d3 = __fadd_rn(__fsub_rn(sumx, __fmul_rn(2.0f, a3)), sk[c0 + 3]);
    if (d0 < best) { best = d0; bidx = c0; }   // strict < -> first index wins
    if (d1 < best) { best = d1; bidx = c0 + 1; }
    if (d2 < best) { best = d2; bidx = c0 + 2; }
    if (d3 < best) { best = d3; bidx = c0 + 3; }
  }

  // cross-wave combine: quarters ascending, strict < keeps lowest index
  bv[wv][lane] = best;
  bi[wv][lane] = bidx;
  __syncthreads();
  if (threadIdx.x < 64) {
    float v = bv[0][threadIdx.x];
    int ii = bi[0][threadIdx.x];
#pragma unroll
    for (int qq = 1; qq < 4; ++qq) {
      const float ov = bv[qq][threadIdx.x];
      if (ov < v) { v = ov; ii = bi[qq][threadIdx.x]; }
    }
    out_codes[R0 + threadIdx.x] = (float)ii;
  }
}

// ---------------- bucket build: count -> scan -> scatter indices ----------------
__global__ __launch_bounds__(256) void vq_count(const float* __restrict__ codes_f,
                                                int* __restrict__ cnt_int) {
  const int row = blockIdx.x * 256 + threadIdx.x;
  atomicAdd(&cnt_int[(int)codes_f[row]], 1);
}

// one block of 256 threads: exclusive prefix over 2048 counts -> cursor
__global__ __launch_bounds__(256) void vq_scan(const int* __restrict__ cnt_int,
                                               int* __restrict__ cursor) {
  __shared__ int sm[256];
  const int t = threadIdx.x;
  int v[8];
  int tot = 0;
#pragma unroll
  for (int j = 0; j < 8; ++j) { v[j] = cnt_int[t * 8 + j]; tot += v[j]; }
  sm[t] = tot;
  __syncthreads();
  int val = tot;
  for (int off = 1; off < 256; off <<= 1) {
    const int add = (t >= off) ? sm[t - off] : 0;
    __syncthreads();
    val += add;
    sm[t] = val;
    __syncthreads();
  }
  int base = val - tot;  // exclusive
#pragma unroll
  for (int j = 0; j < 8; ++j) { cursor[t * 8 + j] = base; base += v[j]; }
}

__global__ __launch_bounds__(256) void vq_scatteridx(
    const float* __restrict__ codes_f, int* __restrict__ cursor,
    int* __restrict__ bucket) {
  const int row = blockIdx.x * 256 + threadIdx.x;
  const int pos = atomicAdd(&cursor[(int)codes_f[row]], 1);
  bucket[pos] = row;
}

// ---------------- per-code segmented sum: one wave per code, lane = d ----------
// After vq_scatteridx, cursor[c] = end of bucket segment; start = end - cnt.
// Plain register accumulation -> writes raw sums into out_ksum (no atomics).
__global__ __launch_bounds__(64) void vq_codesum(
    const float* __restrict__ x, const int* __restrict__ cnt_int,
    const int* __restrict__ cursor, const int* __restrict__ bucket,
    float* __restrict__ out_ksum) {
  const int c = blockIdx.x;
  const int lane = threadIdx.x;          // d
  const int cnt = cnt_int[c];
  const int end = cursor[c];
  const int start = end - cnt;
  float acc = 0.f;
  for (int i = start; i < end; ++i) {
    const int row = bucket[i];           // wave-uniform
    const int n = row >> 13;
    const int t = row & (TT - 1);
    acc = __fadd_rn(acc, x[(size_t)n * (DD * TT) + (size_t)lane * TT + t]);
  }
  out_ksum[(size_t)c * DD + lane] = acc;
}

// ---------------- epilogue: pure streaming (no atomics) ----------------
// Grid (1024, 4) x 256 threads; thread = (row, 4 dims). Commit goes to a
// per-block partials array, reduced deterministically in vq_finalize.
__global__ __launch_bounds__(256) void vq_epi(
    const float* __restrict__ x, const float* __restrict__ k,
    const float* __restrict__ codes_f, float* __restrict__ out_xd,
    float* __restrict__ partial) {
  const int lane = threadIdx.x & 63;
  const int q = threadIdx.x >> 6;          // 0..3
  const int row = blockIdx.x * 64 + lane;
  const int n = row >> 13;
  const int t = row & (TT - 1);
  const int d0 = blockIdx.y * 16 + q * 4;  // this thread's 4 dims

  const int code = (int)codes_f[row];

  const float* xp = x + (size_t)n * (DD * TT) + t;
  float* xd_base = out_xd + (size_t)n * (DD * TT) + t;

  const float4 kq = ((const float4*)k)[(size_t)code * 16 + (d0 >> 2)];

  float csum = 0.f;
#pragma unroll
  for (int j = 0; j < 4; ++j) {
    const int d = d0 + j;
    const float xqv = (j == 0) ? kq.x : (j == 1) ? kq.y : (j == 2) ? kq.z : kq.w;
    const float xv = xp[(size_t)d * TT];       // coalesced across lanes
    const float diff = __fsub_rn(xqv, xv);
    xd_base[(size_t)d * TT] = __fadd_rn(xv, diff);
    csum = fmaf(diff, diff, csum);
  }

  __shared__ float cs[4];
#pragma unroll
  for (int off = 32; off >= 1; off >>= 1) csum += __shfl_xor(csum, off);
  if (lane == 0) cs[q] = csum;
  __syncthreads();
  if (threadIdx.x == 0) {
    partial[blockIdx.y * 1024 + blockIdx.x] = (cs[0] + cs[1]) + (cs[2] + cs[3]);
  }
}

// ---------------- finalize: commit reduce + EMA buffers + k_new ----------------
__global__ __launch_bounds__(256) void vq_finalize(
    const float* __restrict__ k, const float* __restrict__ k_sum,
    const float* __restrict__ k_elem, const int* __restrict__ cnt_int,
    const float* __restrict__ partial, float* __restrict__ out_commit,
    float* __restrict__ out_knew, float* __restrict__ out_ksum,
    float* __restrict__ out_kelem) {
  const int i = blockIdx.x * 256 + threadIdx.x;

  if (blockIdx.x == 0) {                    // deterministic commit reduction
    __shared__ float red[256];
    float s = 0.f;
#pragma unroll
    for (int j = 0; j < 16; ++j) s += partial[threadIdx.x * 16 + j];
    red[threadIdx.x] = s;
    __syncthreads();
    for (int off = 128; off >= 1; off >>= 1) {
      if (threadIdx.x < off) red[threadIdx.x] += red[threadIdx.x + off];
      __syncthreads();
    }
    if (threadIdx.x == 0) out_commit[0] = red[0] / 4194304.0f;
  }

  if (i < KK * DD) {
    const int c = i >> 6;
    const float cnt = (float)cnt_int[c];
    const float ke_n = __fadd_rn(__fmul_rn(0.99f, k_elem[c]), __fmul_rn(0.01f, cnt));
    const float s_raw = out_ksum[i];
    const float ks_n = __fadd_rn(__fmul_rn(0.99f, k_sum[i]), __fmul_rn(0.01f, s_raw));
    out_ksum[i] = ks_n;
    out_knew[i] = (ke_n >= 1.0f) ? (ks_n / ke_n) : k[i];
    if ((i & 63) == 0) out_kelem[c] = ke_n;
  }
}

extern "C" void kernel_launch(void* const* d_in, const int* in_sizes, int n_in,
                              void* d_out, int out_size, void* d_ws, size_t ws_size,
                              hipStream_t stream) {
  const float* x = (const float*)d_in[0];
  const float* k = (const float*)d_in[1];
  const float* k_sum = (const float*)d_in[2];
  const float* k_elem = (const float*)d_in[3];

  float* out = (float*)d_out;
  float* out_xd = out;
  float* out_codes = out + OFF_CODES;
  float* out_commit = out + OFF_COMMIT;
  float* out_knew = out + OFF_KNEW;
  float* out_ksum = out + OFF_KSUM;    // raw sums from vq_codesum, EMA'd in place
  float* out_kelem = out + OFF_KELEM;

  char* ws = (char*)d_ws;
  float* sk = (float*)ws;                       // 8 KB
  int* cnt_int = (int*)(ws + 8192);             // 8 KB
  int* cursor = (int*)(ws + 16384);             // 8 KB
  float* partial = (float*)(ws + 24576);        // 16 KB (4096 floats)
  int* bucket = (int*)(ws + 40960);             // 256 KB

  hipMemsetAsync(cnt_int, 0, (size_t)KK * sizeof(int), stream);

  vq_prep<<<(KK + 255) / 256, 256, 0, stream>>>(k, sk);

  vq_argmin<<<NTROWS / 64, 256, 0, stream>>>(x, k, sk, out_codes);

  vq_count<<<NTROWS / 256, 256, 0, stream>>>(out_codes, cnt_int);
  vq_scan<<<1, 256, 0, stream>>>(cnt_int, cursor);
  vq_scatteridx<<<NTROWS / 256, 256, 0, stream>>>(out_codes, cursor, bucket);
  vq_codesum<<<KK, 64, 0, stream>>>(x, cnt_int, cursor, bucket, out_ksum);

  dim3 epi_grid(NTROWS / 64, 4);
  vq_epi<<<epi_grid, 256, 0, stream>>>(x, k, out_codes, out_xd, partial);

  vq_finalize<<<(KK * DD + 255) / 256, 256, 0, stream>>>(
      k, k_sum, k_elem, cnt_int, partial, out_commit, out_knew, out_ksum,
      out_kelem);
}

// Round 11
// 509.309 us; speedup vs baseline: 2.1034x; 1.4581x over previous
//
#include <hip/hip_runtime.h>

#define DD 64
#define TT 8192
#define KK 2048
#define NTROWS 65536

// d_out layout (float offsets), matching reference return order:
// xd[8*64*8192] | codes[65536] | commit[1] | k_new[131072] | k_sum_n[131072] | k_elem_n[2048]
#define OFF_CODES  4194304ull
#define OFF_COMMIT 4259840ull
#define OFF_KNEW   4259841ull
#define OFF_KSUM   4390913ull
#define OFF_KELEM  4521985ull

#define SQ(a) __fmul_rn((a), (a))

// ws layout (bytes): sk f32 [0,8K) | cnt_int [8K,16K) | cursor [16K,24K)
// | commit partials f32 [24K,40K) | bucket int [40K, 40K+256K)

// ---------------- prep: sk[c] = np.sum(k[c]*k[c]) in replicated fp32 ----------
__global__ __launch_bounds__(256) void vq_prep(const float* __restrict__ k,
                                               float* __restrict__ sk) {
  int c = blockIdx.x * 256 + threadIdx.x;
  if (c < KK) {
    const float* v = k + (size_t)c * DD;
    float r[8];
#pragma unroll
    for (int j = 0; j < 8; ++j) r[j] = SQ(v[j]);
#pragma unroll
    for (int i = 8; i < 64; i += 8) {
#pragma unroll
      for (int j = 0; j < 8; ++j) r[j] = __fadd_rn(r[j], SQ(v[i + j]));
    }
    sk[c] = __fadd_rn(
        __fadd_rn(__fadd_rn(r[0], r[1]), __fadd_rn(r[2], r[3])),
        __fadd_rn(__fadd_rn(r[4], r[5]), __fadd_rn(r[6], r[7])));
  }
}

// ---------------- argmin: wave-uniform k, lane = row (validated) --------------
// Also emits xf[row][d] (row-major transpose of x) from the LDS tile with
// coalesced stores — consumed by vq_codesum. xf aliases out_xd; vq_epi
// overwrites it with the real xd afterward (same-stream ordering).
__global__ __launch_bounds__(256) void vq_argmin(
    const float* __restrict__ x, const float* __restrict__ k,
    const float* __restrict__ sk, float* __restrict__ out_codes,
    float* __restrict__ xf) {
  __shared__ float xs[64][65];       // 16640 B
  __shared__ float bv[4][64];
  __shared__ int bi[4][64];

  const int lane = threadIdx.x & 63;       // row within block
  const int wv = threadIdx.x >> 6;         // code quarter

  const int R0 = blockIdx.x * 64;
  const int n = R0 >> 13;                  // T = 8192
  const int t0 = R0 & (TT - 1);

  // ---- stage 64 rows into LDS, coalesced ----
  {
    const float* xb = x + (size_t)n * (DD * TT) + t0;
    const int tt = threadIdx.x & 63;
    const int dq = threadIdx.x >> 6;       // 0..3
#pragma unroll
    for (int chunk = 0; chunk < 16; ++chunk) {
      const int d = chunk * 4 + dq;
      xs[tt][d] = xb[(size_t)d * TT + tt];
    }
  }
  __syncthreads();

  // ---- emit transpose tile: xf[R0+row][d], fully coalesced float4 stores ----
  {
    const int row = threadIdx.x >> 2;          // 0..63
    const int dq = (threadIdx.x & 3) * 16;     // 4 threads cover one row
    float4* dst = (float4*)(xf + (size_t)(R0 + row) * DD + dq);
#pragma unroll
    for (int j = 0; j < 4; ++j) {
      dst[j] = make_float4(xs[row][dq + 4 * j], xs[row][dq + 4 * j + 1],
                           xs[row][dq + 4 * j + 2], xs[row][dq + 4 * j + 3]);
    }
  }

  // np's ||x||^2: 8 accumulators over stride-8 elements, fixed fold tree
  float sumx;
  {
    float rr[8];
#pragma unroll
    for (int j = 0; j < 8; ++j) rr[j] = SQ(xs[lane][j]);
#pragma unroll
    for (int i = 8; i < 64; i += 8) {
#pragma unroll
      for (int j = 0; j < 8; ++j) rr[j] = __fadd_rn(rr[j], SQ(xs[lane][i + j]));
    }
    sumx = __fadd_rn(
        __fadd_rn(__fadd_rn(rr[0], rr[1]), __fadd_rn(rr[2], rr[3])),
        __fadd_rn(__fadd_rn(rr[4], rr[5]), __fadd_rn(rr[6], rr[7])));
  }

  // wave-uniform code base (force SGPR)
  const int qbase = __builtin_amdgcn_readfirstlane(wv) * (KK / 4);

  float best = 3.402823466e38f;
  int bidx = 0;
  for (int cc = 0; cc < KK / 4; cc += 4) {
    const int c0 = qbase + cc;
    const float4* kp0 = (const float4*)(k + (size_t)c0 * DD);        // uniform
    const float4* kp1 = kp0 + 16;
    const float4* kp2 = kp0 + 32;
    const float4* kp3 = kp0 + 48;
    float a0 = 0.f, a1 = 0.f, a2 = 0.f, a3 = 0.f;
#pragma unroll
    for (int i = 0; i < 16; ++i) {
      const float4 xv = *(const float4*)&xs[lane][4 * i];  // one read, 4 codes
      const float4 kv0 = kp0[i];
      const float4 kv1 = kp1[i];
      const float4 kv2 = kp2[i];
      const float4 kv3 = kp3[i];
      a0 = fmaf(xv.x, kv0.x, a0);
      a1 = fmaf(xv.x, kv1.x, a1);
      a2 = fmaf(xv.x, kv2.x, a2);
      a3 = fmaf(xv.x, kv3.x, a3);
      a0 = fmaf(xv.y, kv0.y, a0);
      a1 = fmaf(xv.y, kv1.y, a1);
      a2 = fmaf(xv.y, kv2.y, a2);
      a3 = fmaf(xv.y, kv3.y, a3);
      a0 = fmaf(xv.z, kv0.z, a0);
      a1 = fmaf(xv.z, kv1.z, a1);
      a2 = fmaf(xv.z, kv2.z, a2);
      a3 = fmaf(xv.z, kv3.z, a3);
      a0 = fmaf(xv.w, kv0.w, a0);
      a1 = fmaf(xv.w, kv1.w, a1);
      a2 = fmaf(xv.w, kv2.w, a2);
      a3 = fmaf(xv.w, kv3.w, a3);
    }
    const float d0 = __fadd_rn(__fsub_rn(sumx, __fmul_rn(2.0f, a0)), sk[c0]);
    const float d1 = __fadd_rn(__fsub_rn(sumx, __fmul_rn(2.0f, a1)), sk[c0 + 1]);
    const float d2 = __fadd_rn(__fsub_rn(sumx, __fmul_rn(2.0f, a2)), sk[c0 + 2]);
    const float d3 = __fadd_rn(__fsub_rn(sumx, __fmul_rn(2.0f, a3)), sk[c0 + 3]);
    if (d0 < best) { best = d0; bidx = c0; }   // strict < -> first index wins
    if (d1 < best) { best = d1; bidx = c0 + 1; }
    if (d2 < best) { best = d2; bidx = c0 + 2; }
    if (d3 < best) { best = d3; bidx = c0 + 3; }
  }

  // cross-wave combine: quarters ascending, strict < keeps lowest index
  bv[wv][lane] = best;
  bi[wv][lane] = bidx;
  __syncthreads();
  if (threadIdx.x < 64) {
    float v = bv[0][threadIdx.x];
    int ii = bi[0][threadIdx.x];
#pragma unroll
    for (int qq = 1; qq < 4; ++qq) {
      const float ov = bv[qq][threadIdx.x];
      if (ov < v) { v = ov; ii = bi[qq][threadIdx.x]; }
    }
    out_codes[R0 + threadIdx.x] = (float)ii;
  }
}

// ---------------- bucket build: count -> scan -> scatter indices ----------------
__global__ __launch_bounds__(256) void vq_count(const float* __restrict__ codes_f,
                                                int* __restrict__ cnt_int) {
  const int row = blockIdx.x * 256 + threadIdx.x;
  atomicAdd(&cnt_int[(int)codes_f[row]], 1);
}

// one block of 256 threads: exclusive prefix over 2048 counts -> cursor
__global__ __launch_bounds__(256) void vq_scan(const int* __restrict__ cnt_int,
                                               int* __restrict__ cursor) {
  __shared__ int sm[256];
  const int t = threadIdx.x;
  int v[8];
  int tot = 0;
#pragma unroll
  for (int j = 0; j < 8; ++j) { v[j] = cnt_int[t * 8 + j]; tot += v[j]; }
  sm[t] = tot;
  __syncthreads();
  int val = tot;
  for (int off = 1; off < 256; off <<= 1) {
    const int add = (t >= off) ? sm[t - off] : 0;
    __syncthreads();
    val += add;
    sm[t] = val;
    __syncthreads();
  }
  int base = val - tot;  // exclusive
#pragma unroll
  for (int j = 0; j < 8; ++j) { cursor[t * 8 + j] = base; base += v[j]; }
}

__global__ __launch_bounds__(256) void vq_scatteridx(
    const float* __restrict__ codes_f, int* __restrict__ cursor,
    int* __restrict__ bucket) {
  const int row = blockIdx.x * 256 + threadIdx.x;
  const int pos = atomicAdd(&cursor[(int)codes_f[row]], 1);
  bucket[pos] = row;
}

// ---------------- per-code segmented sum over xf (coalesced) ----------------
// Block = code; 4 waves stride the bucket; lane = d reads xf[row*64+lane] ->
// 64 lanes = 256 contiguous bytes (4 lines/row vs round-10's 64 lines/row,
// which caused 182 MB HBM fetch + L2 thrash). LDS-combine the 4 partials.
__global__ __launch_bounds__(256) void vq_codesum(
    const float* __restrict__ xf, const int* __restrict__ cnt_int,
    const int* __restrict__ cursor, const int* __restrict__ bucket,
    float* __restrict__ out_ksum) {
  __shared__ float part[4][64];
  const int c = blockIdx.x;
  const int lane = threadIdx.x & 63;       // d
  const int w = threadIdx.x >> 6;          // bucket stride phase
  const int cnt = cnt_int[c];
  const int end = cursor[c];
  const int start = end - cnt;
  float acc = 0.f;
  for (int i = start + w; i < end; i += 4) {
    const int row = bucket[i];
    acc = __fadd_rn(acc, xf[(size_t)row * DD + lane]);
  }
  part[w][lane] = acc;
  __syncthreads();
  if (threadIdx.x < 64) {
    out_ksum[(size_t)c * DD + lane] =
        __fadd_rn(__fadd_rn(part[0][lane], part[1][lane]),
                  __fadd_rn(part[2][lane], part[3][lane]));
  }
}

// ---------------- epilogue: pure streaming (no atomics) ----------------
// Grid (1024, 4) x 256 threads; thread = (row, 4 dims). Overwrites xf with
// the real xd. Commit -> per-block partials, reduced in vq_finalize.
__global__ __launch_bounds__(256) void vq_epi(
    const float* __restrict__ x, const float* __restrict__ k,
    const float* __restrict__ codes_f, float* __restrict__ out_xd,
    float* __restrict__ partial) {
  const int lane = threadIdx.x & 63;
  const int q = threadIdx.x >> 6;          // 0..3
  const int row = blockIdx.x * 64 + lane;
  const int n = row >> 13;
  const int t = row & (TT - 1);
  const int d0 = blockIdx.y * 16 + q * 4;  // this thread's 4 dims

  const int code = (int)codes_f[row];

  const float* xp = x + (size_t)n * (DD * TT) + t;
  float* xd_base = out_xd + (size_t)n * (DD * TT) + t;

  const float4 kq = ((const float4*)k)[(size_t)code * 16 + (d0 >> 2)];

  float csum = 0.f;
#pragma unroll
  for (int j = 0; j < 4; ++j) {
    const int d = d0 + j;
    const float xqv = (j == 0) ? kq.x : (j == 1) ? kq.y : (j == 2) ? kq.z : kq.w;
    const float xv = xp[(size_t)d * TT];       // coalesced across lanes
    const float diff = __fsub_rn(xqv, xv);
    xd_base[(size_t)d * TT] = __fadd_rn(xv, diff);
    csum = fmaf(diff, diff, csum);
  }

  __shared__ float cs[4];
#pragma unroll
  for (int off = 32; off >= 1; off >>= 1) csum += __shfl_xor(csum, off);
  if (lane == 0) cs[q] = csum;
  __syncthreads();
  if (threadIdx.x == 0) {
    partial[blockIdx.y * 1024 + blockIdx.x] = (cs[0] + cs[1]) + (cs[2] + cs[3]);
  }
}

// ---------------- finalize: commit reduce + EMA buffers + k_new ----------------
__global__ __launch_bounds__(256) void vq_finalize(
    const float* __restrict__ k, const float* __restrict__ k_sum,
    const float* __restrict__ k_elem, const int* __restrict__ cnt_int,
    const float* __restrict__ partial, float* __restrict__ out_commit,
    float* __restrict__ out_knew, float* __restrict__ out_ksum,
    float* __restrict__ out_kelem) {
  const int i = blockIdx.x * 256 + threadIdx.x;

  if (blockIdx.x == 0) {                    // deterministic commit reduction
    __shared__ float red[256];
    float s = 0.f;
#pragma unroll
    for (int j = 0; j < 16; ++j) s += partial[threadIdx.x * 16 + j];
    red[threadIdx.x] = s;
    __syncthreads();
    for (int off = 128; off >= 1; off >>= 1) {
      if (threadIdx.x < off) red[threadIdx.x] += red[threadIdx.x + off];
      __syncthreads();
    }
    if (threadIdx.x == 0) out_commit[0] = red[0] / 4194304.0f;
  }

  if (i < KK * DD) {
    const int c = i >> 6;
    const float cnt = (float)cnt_int[c];
    const float ke_n = __fadd_rn(__fmul_rn(0.99f, k_elem[c]), __fmul_rn(0.01f, cnt));
    const float s_raw = out_ksum[i];
    const float ks_n = __fadd_rn(__fmul_rn(0.99f, k_sum[i]), __fmul_rn(0.01f, s_raw));
    out_ksum[i] = ks_n;
    out_knew[i] = (ke_n >= 1.0f) ? (ks_n / ke_n) : k[i];
    if ((i & 63) == 0) out_kelem[c] = ke_n;
  }
}

extern "C" void kernel_launch(void* const* d_in, const int* in_sizes, int n_in,
                              void* d_out, int out_size, void* d_ws, size_t ws_size,
                              hipStream_t stream) {
  const float* x = (const float*)d_in[0];
  const float* k = (const float*)d_in[1];
  const float* k_sum = (const float*)d_in[2];
  const float* k_elem = (const float*)d_in[3];

  float* out = (float*)d_out;
  float* out_xd = out;                 // doubles as xf scratch until vq_epi
  float* out_codes = out + OFF_CODES;
  float* out_commit = out + OFF_COMMIT;
  float* out_knew = out + OFF_KNEW;
  float* out_ksum = out + OFF_KSUM;    // raw sums from vq_codesum, EMA'd in place
  float* out_kelem = out + OFF_KELEM;

  char* ws = (char*)d_ws;
  float* sk = (float*)ws;                       // 8 KB
  int* cnt_int = (int*)(ws + 8192);             // 8 KB
  int* cursor = (int*)(ws + 16384);             // 8 KB
  float* partial = (float*)(ws + 24576);        // 16 KB (4096 floats)
  int* bucket = (int*)(ws + 40960);             // 256 KB

  hipMemsetAsync(cnt_int, 0, (size_t)KK * sizeof(int), stream);

  vq_prep<<<(KK + 255) / 256, 256, 0, stream>>>(k, sk);

  vq_argmin<<<NTROWS / 64, 256, 0, stream>>>(x, k, sk, out_codes, out_xd);

  vq_count<<<NTROWS / 256, 256, 0, stream>>>(out_codes, cnt_int);
  vq_scan<<<1, 256, 0, stream>>>(cnt_int, cursor);
  vq_scatteridx<<<NTROWS / 256, 256, 0, stream>>>(out_codes, cursor, bucket);
  vq_codesum<<<KK, 256, 0, stream>>>(out_xd, cnt_int, cursor, bucket, out_ksum);

  dim3 epi_grid(NTROWS / 64, 4);
  vq_epi<<<epi_grid, 256, 0, stream>>>(x, k, out_codes, out_xd, partial);

  vq_finalize<<<(KK * DD + 255) / 256, 256, 0, stream>>>(
      k, k_sum, k_elem, cnt_int, partial, out_commit, out_knew, out_ksum,
      out_kelem);
}